// Round 1
// baseline (9996.475 us; speedup 1.0000x reference)
//
#include <hip/hip_runtime.h>

#define D 128

// ---------------- small helper kernels ----------------

__global__ __launch_bounds__(256) void count_kernel(const int* __restrict__ dst,
                                                    float* __restrict__ cnt, int n) {
  int i = blockIdx.x * 256 + threadIdx.x;
  if (i < n) atomicAdd(&cnt[dst[i]], 1.0f);
}

__global__ __launch_bounds__(256) void invert_kernel(float* __restrict__ c, int n) {
  int i = blockIdx.x * 256 + threadIdx.x;
  if (i < n) c[i] = 1.0f / fmaxf(c[i], 1.0f);
}

__global__ __launch_bounds__(256) void addvec_kernel(const float* __restrict__ a,
                                                     const float* __restrict__ b,
                                                     float* __restrict__ o, int n) {
  int i = blockIdx.x * 256 + threadIdx.x;
  if (i < n) o[i] = a[i] + b[i];
}

// ---------------- dense linear: out[n,128] = (relu?)X[n,128] @ W[128,128]^T (+bias) ----------------
// Block: 256 threads, 32 rows per block. W staged transposed in LDS as Ws[k][c]
// (pad row to 132 floats: keeps 16B alignment for b128 reads, breaks the worst
// bank conflicts on the staging writes). X tile staged as Xs[32][128].
// Thread (tx=tid&31, ty=tid>>5) computes a 4-row x 4-col register tile; k
// unrolled by 4 -> per k-step: 8 x ds_read_b128 vs 64 FMAs (compute-bound-ish).

template<bool RELU, bool BIAS>
__global__ __launch_bounds__(256) void linear128_kernel(
    const float* __restrict__ X, const float* __restrict__ W,
    const float* __restrict__ bias, float* __restrict__ out, int nrows) {
  __shared__ float Ws[D][D + 4];
  __shared__ float Xs[32][D];
  const int tid = threadIdx.x;

  // stage W transposed: W is [c][k] row-major; write Ws[k][c]
  for (int i = tid; i < D * D; i += 256) {
    int c = i >> 7, k = i & 127;
    Ws[k][c] = W[i];
  }

  const long row0 = (long)blockIdx.x * 32;
  const int limit = nrows - (int)row0;  // rows valid in this block
  const float4* X4 = reinterpret_cast<const float4*>(X) + row0 * (D / 4);
  for (int i = tid; i < 32 * (D / 4); i += 256) {
    int r = i >> 5;
    if (r < limit) {
      float4 v = X4[i];
      if (RELU) {
        v.x = fmaxf(v.x, 0.f); v.y = fmaxf(v.y, 0.f);
        v.z = fmaxf(v.z, 0.f); v.w = fmaxf(v.w, 0.f);
      }
      *reinterpret_cast<float4*>(&Xs[r][(i & 31) * 4]) = v;
    }
  }
  __syncthreads();

  const int tx = tid & 31, ty = tid >> 5;
  const int c0 = tx * 4, r0 = ty * 4;
  float acc[4][4] = {};

#pragma unroll 4
  for (int k = 0; k < D; k += 4) {
    float4 xr[4], wr[4];
#pragma unroll
    for (int i = 0; i < 4; i++)
      xr[i] = *reinterpret_cast<const float4*>(&Xs[r0 + i][k]);
#pragma unroll
    for (int kk = 0; kk < 4; kk++)
      wr[kk] = *reinterpret_cast<const float4*>(&Ws[k + kk][c0]);
#pragma unroll
    for (int i = 0; i < 4; i++) {
      const float* xi = reinterpret_cast<const float*>(&xr[i]);
#pragma unroll
      for (int kk = 0; kk < 4; kk++) {
        float xs = xi[kk];
        acc[i][0] += xs * wr[kk].x;
        acc[i][1] += xs * wr[kk].y;
        acc[i][2] += xs * wr[kk].z;
        acc[i][3] += xs * wr[kk].w;
      }
    }
  }

  float4 bv = make_float4(0.f, 0.f, 0.f, 0.f);
  if (BIAS) bv = *reinterpret_cast<const float4*>(bias + c0);

  float* orow = out + row0 * D;
#pragma unroll
  for (int i = 0; i < 4; i++) {
    int r = r0 + i;
    if (r < limit) {
      float4 v = make_float4(acc[i][0] + bv.x, acc[i][1] + bv.y,
                             acc[i][2] + bv.z, acc[i][3] + bv.w);
      *reinterpret_cast<float4*>(orow + (long)r * D + c0) = v;
    }
  }
}

// ---------------- scatter: acc[dst] += y[src] * invc[dst] ----------------
// 32 threads per edge, float4 per thread (512B row). f32 global atomics.

__global__ __launch_bounds__(256) void scatter_kernel(
    const float* __restrict__ Y, const int* __restrict__ src,
    const int* __restrict__ dst, const float* __restrict__ invc,
    float* __restrict__ acc, int nedges) {
  long g = (long)blockIdx.x * 256 + threadIdx.x;
  int e = (int)(g >> 5);
  if (e >= nedges) return;
  int lane = (int)(g & 31);
  int s = src[e], d = dst[e];
  float sc = invc[d];
  float4 v = reinterpret_cast<const float4*>(Y + (size_t)s * D)[lane];
  float* ap = acc + (size_t)d * D + lane * 4;
  atomicAdd(ap + 0, v.x * sc);
  atomicAdd(ap + 1, v.y * sc);
  atomicAdd(ap + 2, v.z * sc);
  atomicAdd(ap + 3, v.w * sc);
}

// ---------------- launch ----------------

extern "C" void kernel_launch(void* const* d_in, const int* in_sizes, int n_in,
                              void* d_out, int out_size, void* d_ws, size_t ws_size,
                              hipStream_t stream) {
  const float* x_drug = (const float*)d_in[0];
  const float* x_prot = (const float*)d_in[1];
  const float* Wl0dp = (const float*)d_in[2];  const float* b0dp = (const float*)d_in[3];  const float* Wr0dp = (const float*)d_in[4];
  const float* Wl0pd = (const float*)d_in[5];  const float* b0pd = (const float*)d_in[6];  const float* Wr0pd = (const float*)d_in[7];
  const float* Wl0dd = (const float*)d_in[8];  const float* b0dd = (const float*)d_in[9];  const float* Wr0dd = (const float*)d_in[10];
  const float* Wl1dp = (const float*)d_in[11]; const float* b1dp = (const float*)d_in[12]; const float* Wr1dp = (const float*)d_in[13];
  const float* Wl1pd = (const float*)d_in[14]; const float* b1pd = (const float*)d_in[15]; const float* Wr1pd = (const float*)d_in[16];
  const float* Wl1dd = (const float*)d_in[17]; const float* b1dd = (const float*)d_in[18]; const float* Wr1dd = (const float*)d_in[19];
  const int* e_dp_s = (const int*)d_in[20]; const int* e_dp_d = (const int*)d_in[21];
  const int* e_pd_s = (const int*)d_in[22]; const int* e_pd_d = (const int*)d_in[23];
  const int* e_dd_s = (const int*)d_in[24]; const int* e_dd_d = (const int*)d_in[25];

  const int ND = in_sizes[0] / D;   // 200000
  const int NP = in_sizes[1] / D;   // 100000
  const int E_dp = in_sizes[20], E_pd = in_sizes[22], E_dd = in_sizes[24];

  // workspace layout (floats)
  float* ws = (float*)d_ws;
  float* accD = ws;                           // ND*D
  float* accP = accD + (size_t)ND * D;        // NP*D
  float* ybuf = accP + (size_t)NP * D;        // ND*D (max src rows)
  float* c_dp = ybuf + (size_t)ND * D;        // NP
  float* c_pd = c_dp + NP;                    // ND
  float* c_dd = c_pd + ND;                    // ND
  float* Wsum = c_dd + ND;                    // D*D
  float* bsum = Wsum + D * D;                 // D

  auto cdiv = [](long a, long b) { return (int)((a + b - 1) / b); };

  // ---- counts (layer-invariant): cnt -> 1/max(cnt,1) ----
  hipMemsetAsync(c_dp, 0, (size_t)(NP + ND + ND) * sizeof(float), stream);
  count_kernel<<<cdiv(E_dp, 256), 256, 0, stream>>>(e_dp_d, c_dp, E_dp);
  count_kernel<<<cdiv(E_pd, 256), 256, 0, stream>>>(e_pd_d, c_pd, E_pd);
  count_kernel<<<cdiv(E_dd, 256), 256, 0, stream>>>(e_dd_d, c_dd, E_dd);
  invert_kernel<<<cdiv(NP, 256), 256, 0, stream>>>(c_dp, NP);
  invert_kernel<<<cdiv(ND, 256), 256, 0, stream>>>(c_pd, ND);
  invert_kernel<<<cdiv(ND, 256), 256, 0, stream>>>(c_dd, ND);

  auto linear = [&](const float* X, const float* W, const float* bias,
                    float* out, int n, bool relu, bool bias_on) {
    dim3 grid(cdiv(n, 32));
    if (relu) {
      if (bias_on) linear128_kernel<true, true><<<grid, 256, 0, stream>>>(X, W, bias, out, n);
      else         linear128_kernel<true, false><<<grid, 256, 0, stream>>>(X, W, bias, out, n);
    } else {
      if (bias_on) linear128_kernel<false, true><<<grid, 256, 0, stream>>>(X, W, bias, out, n);
      else         linear128_kernel<false, false><<<grid, 256, 0, stream>>>(X, W, bias, out, n);
    }
  };
  auto scatter = [&](const float* Y, const int* s, const int* d2,
                     const float* invc, float* acc, int ne) {
    scatter_kernel<<<cdiv((long)ne * 32, 256), 256, 0, stream>>>(Y, s, d2, invc, acc, ne);
  };

  auto run_layer = [&](const float* xd, const float* xp,
                       const float* Wldp, const float* bdp, const float* Wrdp,
                       const float* Wlpd, const float* bpd, const float* Wrpd,
                       const float* Wldd, const float* bdd, const float* Wrdd,
                       float* outD, float* outP, bool relu_in) {
    // combined lin_r for drug dst (pd + dd share x_dst = xd)
    addvec_kernel<<<cdiv(D * D, 256), 256, 0, stream>>>(Wrpd, Wrdd, Wsum, D * D);
    addvec_kernel<<<1, 256, 0, stream>>>(bpd, bdd, bsum, D);
    // init accumulators with lin_r(x_dst) + bias
    linear(xp, Wrdp, bdp, outP, NP, relu_in, true);
    linear(xd, Wsum, bsum, outD, ND, relu_in, true);
    // relation dp: drugs -> proteins
    linear(xd, Wldp, nullptr, ybuf, ND, relu_in, false);
    scatter(ybuf, e_dp_s, e_dp_d, c_dp, outP, E_dp);
    // relation pd: proteins -> drugs
    linear(xp, Wlpd, nullptr, ybuf, NP, relu_in, false);
    scatter(ybuf, e_pd_s, e_pd_d, c_pd, outD, E_pd);
    // relation dd: drugs -> drugs
    linear(xd, Wldd, nullptr, ybuf, ND, relu_in, false);
    scatter(ybuf, e_dd_s, e_dd_d, c_dd, outD, E_dd);
  };

  float* outD1 = (float*)d_out;                 // first ND*D of output
  float* outP1 = outD1 + (size_t)ND * D;        // next NP*D

  // layer 0: inputs are the raw embeddings, outputs pre-relu into ws
  run_layer(x_drug, x_prot,
            Wl0dp, b0dp, Wr0dp, Wl0pd, b0pd, Wr0pd, Wl0dd, b0dd, Wr0dd,
            accD, accP, /*relu_in=*/false);
  // layer 1: consumers apply relu on load; write directly to d_out
  run_layer(accD, accP,
            Wl1dp, b1dp, Wr1dp, Wl1pd, b1pd, Wr1pd, Wl1dd, b1dd, Wr1dd,
            outD1, outP1, /*relu_in=*/true);
}

// Round 2
// 2855.770 us; speedup vs baseline: 3.5004x; 3.5004x over previous
//
#include <hip/hip_runtime.h>

#define D 128

// ---------------- small helper kernels ----------------

__global__ __launch_bounds__(256) void addvec_kernel(const float* __restrict__ a,
                                                     const float* __restrict__ b,
                                                     float* __restrict__ o, int n) {
  int i = blockIdx.x * 256 + threadIdx.x;
  if (i < n) o[i] = a[i] + b[i];
}

// ---------------- CSR build ----------------

__global__ __launch_bounds__(256) void count_int_kernel(const int* __restrict__ dst,
                                                        int* __restrict__ cnt, int n) {
  int i = blockIdx.x * 256 + threadIdx.x;
  if (i < n) atomicAdd(&cnt[dst[i]], 1);
}

__global__ __launch_bounds__(256) void blocksum_kernel(const int* __restrict__ cnt,
                                                       int* __restrict__ bsums, int n) {
  __shared__ int sh[256];
  int i = blockIdx.x * 256 + threadIdx.x;
  sh[threadIdx.x] = (i < n) ? cnt[i] : 0;
  __syncthreads();
#pragma unroll
  for (int off = 128; off > 0; off >>= 1) {
    if (threadIdx.x < off) sh[threadIdx.x] += sh[threadIdx.x + off];
    __syncthreads();
  }
  if (threadIdx.x == 0) bsums[blockIdx.x] = sh[0];
}

// single-block exclusive scan of bsums (in place), looping over chunks of 256
__global__ __launch_bounds__(256) void scan_bsums_kernel(int* __restrict__ bsums, int nb) {
  __shared__ int sh[256];
  __shared__ int carry;
  if (threadIdx.x == 0) carry = 0;
  __syncthreads();
  for (int base = 0; base < nb; base += 256) {
    int i = base + threadIdx.x;
    int v = (i < nb) ? bsums[i] : 0;
    sh[threadIdx.x] = v;
    __syncthreads();
#pragma unroll
    for (int off = 1; off < 256; off <<= 1) {
      int t = (threadIdx.x >= off) ? sh[threadIdx.x - off] : 0;
      __syncthreads();
      sh[threadIdx.x] += t;
      __syncthreads();
    }
    int incl = sh[threadIdx.x];
    if (i < nb) bsums[i] = carry + incl - v;  // exclusive
    __syncthreads();
    if (threadIdx.x == 0) carry += sh[255];
    __syncthreads();
  }
}

__global__ __launch_bounds__(256) void scan_finalize_kernel(const int* __restrict__ cnt,
                                                            const int* __restrict__ bsums,
                                                            int* __restrict__ rowptr,
                                                            int n, int total) {
  __shared__ int sh[256];
  int i = blockIdx.x * 256 + threadIdx.x;
  int v = (i < n) ? cnt[i] : 0;
  sh[threadIdx.x] = v;
  __syncthreads();
#pragma unroll
  for (int off = 1; off < 256; off <<= 1) {
    int t = (threadIdx.x >= off) ? sh[threadIdx.x - off] : 0;
    __syncthreads();
    sh[threadIdx.x] += t;
    __syncthreads();
  }
  if (i < n) {
    rowptr[i] = bsums[blockIdx.x] + sh[threadIdx.x] - v;  // exclusive prefix
    if (i == n - 1) rowptr[n] = total;
  }
}

__global__ __launch_bounds__(256) void fill_kernel(const int* __restrict__ src,
                                                   const int* __restrict__ dst,
                                                   int* __restrict__ cursor,
                                                   int* __restrict__ slots, int n) {
  int i = blockIdx.x * 256 + threadIdx.x;
  if (i < n) {
    int pos = atomicAdd(&cursor[dst[i]], 1);
    slots[pos] = src[i];
  }
}

// ---------------- dense linear: out[n,128] = (relu?)X[n,128] @ W[128,128]^T (+bias) ----------------

template<bool RELU, bool BIAS>
__global__ __launch_bounds__(256) void linear128_kernel(
    const float* __restrict__ X, const float* __restrict__ W,
    const float* __restrict__ bias, float* __restrict__ out, int nrows) {
  __shared__ float Ws[D][D + 4];
  __shared__ float Xs[32][D];
  const int tid = threadIdx.x;

  for (int i = tid; i < D * D; i += 256) {
    int c = i >> 7, k = i & 127;
    Ws[k][c] = W[i];
  }

  const long row0 = (long)blockIdx.x * 32;
  const int limit = nrows - (int)row0;
  const float4* X4 = reinterpret_cast<const float4*>(X) + row0 * (D / 4);
  for (int i = tid; i < 32 * (D / 4); i += 256) {
    int r = i >> 5;
    if (r < limit) {
      float4 v = X4[i];
      if (RELU) {
        v.x = fmaxf(v.x, 0.f); v.y = fmaxf(v.y, 0.f);
        v.z = fmaxf(v.z, 0.f); v.w = fmaxf(v.w, 0.f);
      }
      *reinterpret_cast<float4*>(&Xs[r][(i & 31) * 4]) = v;
    }
  }
  __syncthreads();

  const int tx = tid & 31, ty = tid >> 5;
  const int c0 = tx * 4, r0 = ty * 4;
  float acc[4][4] = {};

#pragma unroll 4
  for (int k = 0; k < D; k += 4) {
    float4 xr[4], wr[4];
#pragma unroll
    for (int i = 0; i < 4; i++)
      xr[i] = *reinterpret_cast<const float4*>(&Xs[r0 + i][k]);
#pragma unroll
    for (int kk = 0; kk < 4; kk++)
      wr[kk] = *reinterpret_cast<const float4*>(&Ws[k + kk][c0]);
#pragma unroll
    for (int i = 0; i < 4; i++) {
      const float* xi = reinterpret_cast<const float*>(&xr[i]);
#pragma unroll
      for (int kk = 0; kk < 4; kk++) {
        float xs = xi[kk];
        acc[i][0] += xs * wr[kk].x;
        acc[i][1] += xs * wr[kk].y;
        acc[i][2] += xs * wr[kk].z;
        acc[i][3] += xs * wr[kk].w;
      }
    }
  }

  float4 bv = make_float4(0.f, 0.f, 0.f, 0.f);
  if (BIAS) bv = *reinterpret_cast<const float4*>(bias + c0);

  float* orow = out + row0 * D;
#pragma unroll
  for (int i = 0; i < 4; i++) {
    int r = r0 + i;
    if (r < limit) {
      float4 v = make_float4(acc[i][0] + bv.x, acc[i][1] + bv.y,
                             acc[i][2] + bv.z, acc[i][3] + bv.w);
      *reinterpret_cast<float4*>(orow + (long)r * D + c0) = v;
    }
  }
}

// ---------------- gather: acc[d] += mean_{s in N(d)} Y[s]  (CSR, no atomics) ----------------
// 32 threads per dst node, float4/lane covers the 128-float row. Each group
// owns its output row -> plain read-modify-write.

__global__ __launch_bounds__(256) void gather_kernel(
    const float* __restrict__ Y, const int* __restrict__ rowptr,
    const int* __restrict__ slots, float* __restrict__ acc, int nnodes) {
  long g = (long)blockIdx.x * 256 + threadIdx.x;
  int node = (int)(g >> 5);
  if (node >= nnodes) return;
  int lane = (int)(g & 31);
  int s0 = rowptr[node], s1 = rowptr[node + 1];
  float4 sum = make_float4(0.f, 0.f, 0.f, 0.f);
  const float4* Y4 = reinterpret_cast<const float4*>(Y);
  for (int j = s0; j < s1; ++j) {
    int s = slots[j];
    float4 v = Y4[(size_t)s * 32 + lane];
    sum.x += v.x; sum.y += v.y; sum.z += v.z; sum.w += v.w;
  }
  float inv = 1.0f / fmaxf((float)(s1 - s0), 1.0f);
  float4* ap = reinterpret_cast<float4*>(acc) + (size_t)node * 32 + lane;
  float4 a = *ap;
  a.x += sum.x * inv; a.y += sum.y * inv;
  a.z += sum.z * inv; a.w += sum.w * inv;
  *ap = a;
}

// ---------------- launch ----------------

extern "C" void kernel_launch(void* const* d_in, const int* in_sizes, int n_in,
                              void* d_out, int out_size, void* d_ws, size_t ws_size,
                              hipStream_t stream) {
  const float* x_drug = (const float*)d_in[0];
  const float* x_prot = (const float*)d_in[1];
  const float* Wl0dp = (const float*)d_in[2];  const float* b0dp = (const float*)d_in[3];  const float* Wr0dp = (const float*)d_in[4];
  const float* Wl0pd = (const float*)d_in[5];  const float* b0pd = (const float*)d_in[6];  const float* Wr0pd = (const float*)d_in[7];
  const float* Wl0dd = (const float*)d_in[8];  const float* b0dd = (const float*)d_in[9];  const float* Wr0dd = (const float*)d_in[10];
  const float* Wl1dp = (const float*)d_in[11]; const float* b1dp = (const float*)d_in[12]; const float* Wr1dp = (const float*)d_in[13];
  const float* Wl1pd = (const float*)d_in[14]; const float* b1pd = (const float*)d_in[15]; const float* Wr1pd = (const float*)d_in[16];
  const float* Wl1dd = (const float*)d_in[17]; const float* b1dd = (const float*)d_in[18]; const float* Wr1dd = (const float*)d_in[19];
  const int* e_dp_s = (const int*)d_in[20]; const int* e_dp_d = (const int*)d_in[21];
  const int* e_pd_s = (const int*)d_in[22]; const int* e_pd_d = (const int*)d_in[23];
  const int* e_dd_s = (const int*)d_in[24]; const int* e_dd_d = (const int*)d_in[25];

  const int ND = in_sizes[0] / D;   // 200000
  const int NP = in_sizes[1] / D;   // 100000
  const int E_dp = in_sizes[20], E_pd = in_sizes[22], E_dd = in_sizes[24];

  // workspace layout
  float* ws = (float*)d_ws;
  float* accD = ws;                           // ND*D
  float* accP = accD + (size_t)ND * D;        // NP*D
  float* ybuf = accP + (size_t)NP * D;        // ND*D
  float* Wsum = ybuf + (size_t)ND * D;        // D*D
  float* bsum = Wsum + D * D;                 // D
  int* iws   = (int*)(bsum + D);
  int* rowptr = iws;                          // max ND+1
  int* cnt    = rowptr + (ND + 1);            // max ND (doubles as cursor)
  int* bsums  = cnt + ND;                     // ~1024
  int* slots  = bsums + 1024;                 // E (800000)

  auto cdiv = [](long a, long b) { return (int)((a + b - 1) / b); };

  auto linear = [&](const float* X, const float* W, const float* bias,
                    float* out, int n, bool relu, bool bias_on) {
    dim3 grid(cdiv(n, 32));
    if (relu) {
      if (bias_on) linear128_kernel<true, true><<<grid, 256, 0, stream>>>(X, W, bias, out, n);
      else         linear128_kernel<true, false><<<grid, 256, 0, stream>>>(X, W, bias, out, n);
    } else {
      if (bias_on) linear128_kernel<false, true><<<grid, 256, 0, stream>>>(X, W, bias, out, n);
      else         linear128_kernel<false, false><<<grid, 256, 0, stream>>>(X, W, bias, out, n);
    }
  };

  // build CSR (rowptr, slots) for one relation, then gather ybuf into acc
  auto csr_gather = [&](const int* esrc, const int* edst, int ne, int ndst, float* acc) {
    int nb = cdiv(ndst, 256);
    hipMemsetAsync(cnt, 0, (size_t)ndst * sizeof(int), stream);
    count_int_kernel<<<cdiv(ne, 256), 256, 0, stream>>>(edst, cnt, ne);
    blocksum_kernel<<<nb, 256, 0, stream>>>(cnt, bsums, ndst);
    scan_bsums_kernel<<<1, 256, 0, stream>>>(bsums, nb);
    scan_finalize_kernel<<<nb, 256, 0, stream>>>(cnt, bsums, rowptr, ndst, ne);
    // cursor := rowptr (reuse cnt buffer as cursor)
    hipMemcpyAsync(cnt, rowptr, (size_t)ndst * sizeof(int), hipMemcpyDeviceToDevice, stream);
    fill_kernel<<<cdiv(ne, 256), 256, 0, stream>>>(esrc, edst, cnt, slots, ne);
    gather_kernel<<<cdiv((long)ndst * 32, 256), 256, 0, stream>>>(ybuf, rowptr, slots, acc, ndst);
  };

  auto run_layer = [&](const float* xd, const float* xp,
                       const float* Wldp, const float* bdp, const float* Wrdp,
                       const float* Wlpd, const float* bpd, const float* Wrpd,
                       const float* Wldd, const float* bdd, const float* Wrdd,
                       float* outD, float* outP, bool relu_in) {
    // combined lin_r for drug dst (pd + dd share x_dst = xd)
    addvec_kernel<<<cdiv(D * D, 256), 256, 0, stream>>>(Wrpd, Wrdd, Wsum, D * D);
    addvec_kernel<<<1, 256, 0, stream>>>(bpd, bdd, bsum, D);
    // init accumulators with lin_r(x_dst) + bias
    linear(xp, Wrdp, bdp, outP, NP, relu_in, true);
    linear(xd, Wsum, bsum, outD, ND, relu_in, true);
    // relation dp: drugs -> proteins
    linear(xd, Wldp, nullptr, ybuf, ND, relu_in, false);
    csr_gather(e_dp_s, e_dp_d, E_dp, NP, outP);
    // relation pd: proteins -> drugs
    linear(xp, Wlpd, nullptr, ybuf, NP, relu_in, false);
    csr_gather(e_pd_s, e_pd_d, E_pd, ND, outD);
    // relation dd: drugs -> drugs
    linear(xd, Wldd, nullptr, ybuf, ND, relu_in, false);
    csr_gather(e_dd_s, e_dd_d, E_dd, ND, outD);
  };

  float* outD1 = (float*)d_out;
  float* outP1 = outD1 + (size_t)ND * D;

  run_layer(x_drug, x_prot,
            Wl0dp, b0dp, Wr0dp, Wl0pd, b0pd, Wr0pd, Wl0dd, b0dd, Wr0dd,
            accD, accP, /*relu_in=*/false);
  run_layer(accD, accP,
            Wl1dp, b1dp, Wr1dp, Wl1pd, b1pd, Wr1pd, Wl1dd, b1dd, Wr1dd,
            outD1, outP1, /*relu_in=*/true);
}

// Round 3
// 1366.851 us; speedup vs baseline: 7.3135x; 2.0893x over previous
//
#include <hip/hip_runtime.h>

#define D 128

using short8 = __attribute__((ext_vector_type(8))) short;
using f32x4 = __attribute__((ext_vector_type(4))) float;

__device__ inline unsigned short f2bf(float f) {
  unsigned u = __float_as_uint(f);
  u += 0x7fffu + ((u >> 16) & 1u);  // RNE
  return (unsigned short)(u >> 16);
}

// swizzled byte offset within a [128 rows][128 bf16] LDS tile (G4 fix)
__device__ inline int swz(int r, int kbyte) {
  return ((r << 8) + kbyte) ^ ((r & 7) << 4);
}

// ---------------- small helper kernels ----------------

__global__ __launch_bounds__(256) void addvec_kernel(const float* __restrict__ a,
                                                     const float* __restrict__ b,
                                                     float* __restrict__ o, int n) {
  int i = blockIdx.x * 256 + threadIdx.x;
  if (i < n) o[i] = a[i] + b[i];
}

// ---------------- CSR build ----------------

__global__ __launch_bounds__(256) void count_int_kernel(const int* __restrict__ dst,
                                                        int* __restrict__ cnt, int n) {
  int i = blockIdx.x * 256 + threadIdx.x;
  if (i < n) atomicAdd(&cnt[dst[i]], 1);
}

__global__ __launch_bounds__(256) void blocksum_kernel(const int* __restrict__ cnt,
                                                       int* __restrict__ bsums, int n) {
  __shared__ int sh[256];
  int i = blockIdx.x * 256 + threadIdx.x;
  sh[threadIdx.x] = (i < n) ? cnt[i] : 0;
  __syncthreads();
#pragma unroll
  for (int off = 128; off > 0; off >>= 1) {
    if (threadIdx.x < off) sh[threadIdx.x] += sh[threadIdx.x + off];
    __syncthreads();
  }
  if (threadIdx.x == 0) bsums[blockIdx.x] = sh[0];
}

__global__ __launch_bounds__(256) void scan_bsums_kernel(int* __restrict__ bsums, int nb) {
  __shared__ int sh[256];
  __shared__ int carry;
  if (threadIdx.x == 0) carry = 0;
  __syncthreads();
  for (int base = 0; base < nb; base += 256) {
    int i = base + threadIdx.x;
    int v = (i < nb) ? bsums[i] : 0;
    sh[threadIdx.x] = v;
    __syncthreads();
#pragma unroll
    for (int off = 1; off < 256; off <<= 1) {
      int t = (threadIdx.x >= off) ? sh[threadIdx.x - off] : 0;
      __syncthreads();
      sh[threadIdx.x] += t;
      __syncthreads();
    }
    int incl = sh[threadIdx.x];
    if (i < nb) bsums[i] = carry + incl - v;  // exclusive
    __syncthreads();
    if (threadIdx.x == 0) carry += sh[255];
    __syncthreads();
  }
}

__global__ __launch_bounds__(256) void scan_finalize_kernel(const int* __restrict__ cnt,
                                                            const int* __restrict__ bsums,
                                                            int* __restrict__ rowptr,
                                                            int n, int total) {
  __shared__ int sh[256];
  int i = blockIdx.x * 256 + threadIdx.x;
  int v = (i < n) ? cnt[i] : 0;
  sh[threadIdx.x] = v;
  __syncthreads();
#pragma unroll
  for (int off = 1; off < 256; off <<= 1) {
    int t = (threadIdx.x >= off) ? sh[threadIdx.x - off] : 0;
    __syncthreads();
    sh[threadIdx.x] += t;
    __syncthreads();
  }
  if (i < n) {
    rowptr[i] = bsums[blockIdx.x] + sh[threadIdx.x] - v;
    if (i == n - 1) rowptr[n] = total;
  }
}

__global__ __launch_bounds__(256) void fill_kernel(const int* __restrict__ src,
                                                   const int* __restrict__ dst,
                                                   int* __restrict__ cursor,
                                                   int* __restrict__ slots, int n) {
  int i = blockIdx.x * 256 + threadIdx.x;
  if (i < n) {
    int pos = atomicAdd(&cursor[dst[i]], 1);
    slots[pos] = src[i];
  }
}

// ---------------- MFMA GEMM: out[n,128] = (relu?)X[n,128] @ W[128,128]^T (+bias) ----------------
// 256 threads = 4 waves; block tile 128 rows x 128 cols; K=128 in 4 steps of 32.
// X tile and W staged as bf16 in LDS, XOR-swizzled (row-major D=128 bf16 would be a
// 16-way bank conflict on ds_read_b128 -> byte ^= (row&7)<<4 makes it ~2-way = free).
// Per wave: 32 rows -> acc[2][8] f32x4 fragments (64 VGPR). mfma_f32_16x16x32_bf16,
// A lane layout: row=lane&15, k=(lane>>4)*8+j (contiguous 16B per lane); B identical
// on row-major W (out-col = W row). C/D: col=lane&15, row=(lane>>4)*4+reg [m89].

template<bool RELU, bool BIAS, bool OBF16>
__global__ __launch_bounds__(256) void gemm128_kernel(
    const float* __restrict__ X, const float* __restrict__ W,
    const float* __restrict__ bias, void* __restrict__ out, int nrows) {
  __shared__ short lds[2 * D * D];
  short* Xs = lds;
  short* Wsh = lds + D * D;
  const int tid = threadIdx.x;
  const long row0 = (long)blockIdx.x * 128;
  const long rem = (long)nrows - row0;
  const int limit = (int)(rem < 128 ? rem : 128);

  const float4* W4 = reinterpret_cast<const float4*>(W);
  const float4* X4 = reinterpret_cast<const float4*>(X + row0 * D);
#pragma unroll
  for (int j = 0; j < 16; ++j) {
    int idx = tid + j * 256;        // float4 index in 128x128 tile
    int r = idx >> 5;               // row
    int kb = (idx & 31) * 8;        // byte offset of 4 bf16 within row
    float4 wv = W4[idx];
    ushort4 wh = make_ushort4(f2bf(wv.x), f2bf(wv.y), f2bf(wv.z), f2bf(wv.w));
    *reinterpret_cast<ushort4*>((char*)Wsh + swz(r, kb)) = wh;
    float4 xv = make_float4(0.f, 0.f, 0.f, 0.f);
    if (r < limit) xv = X4[idx];
    if (RELU) {
      xv.x = fmaxf(xv.x, 0.f); xv.y = fmaxf(xv.y, 0.f);
      xv.z = fmaxf(xv.z, 0.f); xv.w = fmaxf(xv.w, 0.f);
    }
    ushort4 xh = make_ushort4(f2bf(xv.x), f2bf(xv.y), f2bf(xv.z), f2bf(xv.w));
    *reinterpret_cast<ushort4*>((char*)Xs + swz(r, kb)) = xh;
  }
  __syncthreads();

  const int wv = tid >> 6;
  const int lane = tid & 63;
  const int l15 = lane & 15;
  const int lg = lane >> 4;
  const int rA0 = wv * 32 + l15;

  f32x4 acc[2][8] = {};
#pragma unroll
  for (int t = 0; t < 4; ++t) {
    const int kb = t * 64 + lg * 16;  // bytes: k = t*32 + lg*8
    short8 a0 = *reinterpret_cast<const short8*>((char*)Xs + swz(rA0, kb));
    short8 a1 = *reinterpret_cast<const short8*>((char*)Xs + swz(rA0 + 16, kb));
#pragma unroll
    for (int n = 0; n < 8; ++n) {
      short8 b = *reinterpret_cast<const short8*>((char*)Wsh + swz(n * 16 + l15, kb));
      acc[0][n] = __builtin_amdgcn_mfma_f32_16x16x32_bf16(a0, b, acc[0][n], 0, 0, 0);
      acc[1][n] = __builtin_amdgcn_mfma_f32_16x16x32_bf16(a1, b, acc[1][n], 0, 0, 0);
    }
  }

#pragma unroll
  for (int m = 0; m < 2; ++m) {
#pragma unroll
    for (int n = 0; n < 8; ++n) {
      const int col = n * 16 + l15;
      float bv = 0.f;
      if (BIAS) bv = bias[col];
#pragma unroll
      for (int r = 0; r < 4; ++r) {
        int lrow = wv * 32 + m * 16 + lg * 4 + r;
        if (lrow < limit) {
          float v = acc[m][n][r] + bv;
          if (OBF16)
            reinterpret_cast<unsigned short*>(out)[(row0 + lrow) * D + col] = f2bf(v);
          else
            reinterpret_cast<float*>(out)[(row0 + lrow) * D + col] = v;
        }
      }
    }
  }
}

// ---------------- gather: acc[d] += mean_{s in N(d)} Ybf16[s]  (CSR, no atomics) ----------------

__global__ __launch_bounds__(256) void gather_kernel(
    const unsigned* __restrict__ Y, const int* __restrict__ rowptr,
    const int* __restrict__ slots, float* __restrict__ acc, int nnodes) {
  long g = (long)blockIdx.x * 256 + threadIdx.x;
  int node = (int)(g >> 5);
  if (node >= nnodes) return;
  int lane = (int)(g & 31);
  int s0 = rowptr[node], s1 = rowptr[node + 1];
  float4 sum = make_float4(0.f, 0.f, 0.f, 0.f);
  const uint2* Y2 = reinterpret_cast<const uint2*>(Y);
  for (int j = s0; j < s1; ++j) {
    int s = slots[j];
    uint2 v = Y2[(size_t)s * 32 + lane];
    sum.x += __uint_as_float(v.x << 16);
    sum.y += __uint_as_float(v.x & 0xffff0000u);
    sum.z += __uint_as_float(v.y << 16);
    sum.w += __uint_as_float(v.y & 0xffff0000u);
  }
  float inv = 1.0f / fmaxf((float)(s1 - s0), 1.0f);
  float4* ap = reinterpret_cast<float4*>(acc) + (size_t)node * 32 + lane;
  float4 a = *ap;
  a.x += sum.x * inv; a.y += sum.y * inv;
  a.z += sum.z * inv; a.w += sum.w * inv;
  *ap = a;
}

// ---------------- launch ----------------

extern "C" void kernel_launch(void* const* d_in, const int* in_sizes, int n_in,
                              void* d_out, int out_size, void* d_ws, size_t ws_size,
                              hipStream_t stream) {
  const float* x_drug = (const float*)d_in[0];
  const float* x_prot = (const float*)d_in[1];
  const float* Wl0dp = (const float*)d_in[2];  const float* b0dp = (const float*)d_in[3];  const float* Wr0dp = (const float*)d_in[4];
  const float* Wl0pd = (const float*)d_in[5];  const float* b0pd = (const float*)d_in[6];  const float* Wr0pd = (const float*)d_in[7];
  const float* Wl0dd = (const float*)d_in[8];  const float* b0dd = (const float*)d_in[9];  const float* Wr0dd = (const float*)d_in[10];
  const float* Wl1dp = (const float*)d_in[11]; const float* b1dp = (const float*)d_in[12]; const float* Wr1dp = (const float*)d_in[13];
  const float* Wl1pd = (const float*)d_in[14]; const float* b1pd = (const float*)d_in[15]; const float* Wr1pd = (const float*)d_in[16];
  const float* Wl1dd = (const float*)d_in[17]; const float* b1dd = (const float*)d_in[18]; const float* Wr1dd = (const float*)d_in[19];
  const int* e_dp_s = (const int*)d_in[20]; const int* e_dp_d = (const int*)d_in[21];
  const int* e_pd_s = (const int*)d_in[22]; const int* e_pd_d = (const int*)d_in[23];
  const int* e_dd_s = (const int*)d_in[24]; const int* e_dd_d = (const int*)d_in[25];

  const int ND = in_sizes[0] / D;   // 200000
  const int NP = in_sizes[1] / D;   // 100000
  const int E_dp = in_sizes[20], E_pd = in_sizes[22], E_dd = in_sizes[24];

  // workspace layout
  float* ws = (float*)d_ws;
  float* accD = ws;                               // ND*D f32
  float* accP = accD + (size_t)ND * D;            // NP*D f32
  unsigned short* ybuf = (unsigned short*)(accP + (size_t)NP * D);  // ND*D bf16
  float* Wsum = (float*)(ybuf + (size_t)ND * D);  // D*D
  float* bsum = Wsum + D * D;                     // D
  int* iws    = (int*)(bsum + D);
  int* rp_dp  = iws;                              // NP+1
  int* rp_pd  = rp_dp + (NP + 2);                 // ND+1
  int* rp_dd  = rp_pd + (ND + 2);                 // ND+1
  int* sl_dp  = rp_dd + (ND + 2);                 // E_dp
  int* sl_pd  = sl_dp + E_dp;                     // E_pd
  int* sl_dd  = sl_pd + E_pd;                     // E_dd
  int* cnt    = sl_dd + E_dd;                     // max(ND,NP)
  int* bsums  = cnt + ND;                         // <=1024

  auto cdiv = [](long a, long b) { return (int)((a + b - 1) / b); };

  auto build_csr = [&](const int* esrc, const int* edst, int ne, int ndst,
                       int* rowptr, int* slots) {
    int nb = cdiv(ndst, 256);
    hipMemsetAsync(cnt, 0, (size_t)ndst * sizeof(int), stream);
    count_int_kernel<<<cdiv(ne, 256), 256, 0, stream>>>(edst, cnt, ne);
    blocksum_kernel<<<nb, 256, 0, stream>>>(cnt, bsums, ndst);
    scan_bsums_kernel<<<1, 256, 0, stream>>>(bsums, nb);
    scan_finalize_kernel<<<nb, 256, 0, stream>>>(cnt, bsums, rowptr, ndst, ne);
    hipMemcpyAsync(cnt, rowptr, (size_t)ndst * sizeof(int), hipMemcpyDeviceToDevice, stream);
    fill_kernel<<<cdiv(ne, 256), 256, 0, stream>>>(esrc, edst, cnt, slots, ne);
  };

  auto gemm = [&](const float* X, const float* W, const float* bias,
                  void* out, int n, bool relu, bool bias_on, bool obf16) {
    dim3 grid(cdiv(n, 128));
    if (relu) {
      if (obf16)        gemm128_kernel<true, false, true><<<grid, 256, 0, stream>>>(X, W, bias, out, n);
      else if (bias_on) gemm128_kernel<true, true, false><<<grid, 256, 0, stream>>>(X, W, bias, out, n);
      else              gemm128_kernel<true, false, false><<<grid, 256, 0, stream>>>(X, W, bias, out, n);
    } else {
      if (obf16)        gemm128_kernel<false, false, true><<<grid, 256, 0, stream>>>(X, W, bias, out, n);
      else if (bias_on) gemm128_kernel<false, true, false><<<grid, 256, 0, stream>>>(X, W, bias, out, n);
      else              gemm128_kernel<false, false, false><<<grid, 256, 0, stream>>>(X, W, bias, out, n);
    }
  };
  auto gather = [&](const unsigned short* Y, const int* rowptr, const int* slots,
                    float* acc, int ndst) {
    gather_kernel<<<cdiv((long)ndst * 32, 256), 256, 0, stream>>>(
        (const unsigned*)Y, rowptr, slots, acc, ndst);
  };

  // ---- CSRs (layer-invariant, built once) ----
  build_csr(e_dp_s, e_dp_d, E_dp, NP, rp_dp, sl_dp);
  build_csr(e_pd_s, e_pd_d, E_pd, ND, rp_pd, sl_pd);
  build_csr(e_dd_s, e_dd_d, E_dd, ND, rp_dd, sl_dd);

  auto run_layer = [&](const float* xd, const float* xp,
                       const float* Wldp, const float* bdp, const float* Wrdp,
                       const float* Wlpd, const float* bpd, const float* Wrpd,
                       const float* Wldd, const float* bdd, const float* Wrdd,
                       float* outD, float* outP, bool relu_in) {
    addvec_kernel<<<cdiv(D * D, 256), 256, 0, stream>>>(Wrpd, Wrdd, Wsum, D * D);
    addvec_kernel<<<1, 256, 0, stream>>>(bpd, bdd, bsum, D);
    // init accumulators with lin_r(x_dst) + bias (f32 out)
    gemm(xp, Wrdp, bdp, outP, NP, relu_in, true, false);
    gemm(xd, Wsum, bsum, outD, ND, relu_in, true, false);
    // dp: drugs -> proteins
    gemm(xd, Wldp, nullptr, ybuf, ND, relu_in, false, true);
    gather(ybuf, rp_dp, sl_dp, outP, NP);
    // pd: proteins -> drugs
    gemm(xp, Wlpd, nullptr, ybuf, NP, relu_in, false, true);
    gather(ybuf, rp_pd, sl_pd, outD, ND);
    // dd: drugs -> drugs
    gemm(xd, Wldd, nullptr, ybuf, ND, relu_in, false, true);
    gather(ybuf, rp_dd, sl_dd, outD, ND);
  };

  float* outD1 = (float*)d_out;
  float* outP1 = outD1 + (size_t)ND * D;

  run_layer(x_drug, x_prot,
            Wl0dp, b0dp, Wr0dp, Wl0pd, b0pd, Wr0pd, Wl0dd, b0dd, Wr0dd,
            accD, accP, /*relu_in=*/false);
  run_layer(accD, accP,
            Wl1dp, b1dp, Wr1dp, Wl1pd, b1pd, Wr1pd, Wl1dd, b1dd, Wr1dd,
            outD1, outP1, /*relu_in=*/true);
}

// Round 4
// 1139.741 us; speedup vs baseline: 8.7708x; 1.1993x over previous
//
#include <hip/hip_runtime.h>

#define D 128

using short8 = __attribute__((ext_vector_type(8))) short;
using f32x4 = __attribute__((ext_vector_type(4))) float;

__device__ inline unsigned short f2bf(float f) {
  unsigned u = __float_as_uint(f);
  u += 0x7fffu + ((u >> 16) & 1u);  // RNE
  return (unsigned short)(u >> 16);
}

// swizzled byte offset within a [128 rows][128 bf16] LDS tile (G4 fix)
__device__ inline int swz(int r, int kbyte) {
  return ((r << 8) + kbyte) ^ ((r & 7) << 4);
}

// ---------------- small helper kernels ----------------

__global__ __launch_bounds__(256) void addvec_kernel(const float* __restrict__ a,
                                                     const float* __restrict__ b,
                                                     float* __restrict__ o, int n) {
  int i = blockIdx.x * 256 + threadIdx.x;
  if (i < n) o[i] = a[i] + b[i];
}

// ---------------- CSR build ----------------

__global__ __launch_bounds__(256) void count_int_kernel(const int* __restrict__ dst,
                                                        int* __restrict__ cnt, int n) {
  int i = blockIdx.x * 256 + threadIdx.x;
  if (i < n) atomicAdd(&cnt[dst[i]], 1);
}

__global__ __launch_bounds__(256) void blocksum_kernel(const int* __restrict__ cnt,
                                                       int* __restrict__ bsums, int n) {
  __shared__ int sh[256];
  int i = blockIdx.x * 256 + threadIdx.x;
  sh[threadIdx.x] = (i < n) ? cnt[i] : 0;
  __syncthreads();
#pragma unroll
  for (int off = 128; off > 0; off >>= 1) {
    if (threadIdx.x < off) sh[threadIdx.x] += sh[threadIdx.x + off];
    __syncthreads();
  }
  if (threadIdx.x == 0) bsums[blockIdx.x] = sh[0];
}

__global__ __launch_bounds__(256) void scan_bsums_kernel(int* __restrict__ bsums, int nb) {
  __shared__ int sh[256];
  __shared__ int carry;
  if (threadIdx.x == 0) carry = 0;
  __syncthreads();
  for (int base = 0; base < nb; base += 256) {
    int i = base + threadIdx.x;
    int v = (i < nb) ? bsums[i] : 0;
    sh[threadIdx.x] = v;
    __syncthreads();
#pragma unroll
    for (int off = 1; off < 256; off <<= 1) {
      int t = (threadIdx.x >= off) ? sh[threadIdx.x - off] : 0;
      __syncthreads();
      sh[threadIdx.x] += t;
      __syncthreads();
    }
    int incl = sh[threadIdx.x];
    if (i < nb) bsums[i] = carry + incl - v;  // exclusive
    __syncthreads();
    if (threadIdx.x == 0) carry += sh[255];
    __syncthreads();
  }
}

__global__ __launch_bounds__(256) void scan_finalize_kernel(const int* __restrict__ cnt,
                                                            const int* __restrict__ bsums,
                                                            int* __restrict__ rowptr,
                                                            int n, int total) {
  __shared__ int sh[256];
  int i = blockIdx.x * 256 + threadIdx.x;
  int v = (i < n) ? cnt[i] : 0;
  sh[threadIdx.x] = v;
  __syncthreads();
#pragma unroll
  for (int off = 1; off < 256; off <<= 1) {
    int t = (threadIdx.x >= off) ? sh[threadIdx.x - off] : 0;
    __syncthreads();
    sh[threadIdx.x] += t;
    __syncthreads();
  }
  if (i < n) {
    rowptr[i] = bsums[blockIdx.x] + sh[threadIdx.x] - v;
    if (i == n - 1) rowptr[n] = total;
  }
}

__global__ __launch_bounds__(256) void fill_kernel(const int* __restrict__ src,
                                                   const int* __restrict__ dst,
                                                   int* __restrict__ cursor,
                                                   int* __restrict__ slots, int n) {
  int i = blockIdx.x * 256 + threadIdx.x;
  if (i < n) {
    int pos = atomicAdd(&cursor[dst[i]], 1);
    slots[pos] = src[i];
  }
}

// ---------------- MFMA GEMM: out[n,128] = (relu?)X[n,128] @ W[128,128]^T (+bias) ----------------

template<bool RELU, bool BIAS, bool OBF16>
__global__ __launch_bounds__(256) void gemm128_kernel(
    const float* __restrict__ X, const float* __restrict__ W,
    const float* __restrict__ bias, void* __restrict__ out, int nrows) {
  __shared__ short lds[2 * D * D];
  short* Xs = lds;
  short* Wsh = lds + D * D;
  const int tid = threadIdx.x;
  const long row0 = (long)blockIdx.x * 128;
  const long rem = (long)nrows - row0;
  const int limit = (int)(rem < 128 ? rem : 128);

  const float4* W4 = reinterpret_cast<const float4*>(W);
  const float4* X4 = reinterpret_cast<const float4*>(X + row0 * D);
#pragma unroll
  for (int j = 0; j < 16; ++j) {
    int idx = tid + j * 256;        // float4 index in 128x128 tile
    int r = idx >> 5;               // row
    int kb = (idx & 31) * 8;        // byte offset of 4 bf16 within row
    float4 wv = W4[idx];
    ushort4 wh = make_ushort4(f2bf(wv.x), f2bf(wv.y), f2bf(wv.z), f2bf(wv.w));
    *reinterpret_cast<ushort4*>((char*)Wsh + swz(r, kb)) = wh;
    float4 xv = make_float4(0.f, 0.f, 0.f, 0.f);
    if (r < limit) xv = X4[idx];
    if (RELU) {
      xv.x = fmaxf(xv.x, 0.f); xv.y = fmaxf(xv.y, 0.f);
      xv.z = fmaxf(xv.z, 0.f); xv.w = fmaxf(xv.w, 0.f);
    }
    ushort4 xh = make_ushort4(f2bf(xv.x), f2bf(xv.y), f2bf(xv.z), f2bf(xv.w));
    *reinterpret_cast<ushort4*>((char*)Xs + swz(r, kb)) = xh;
  }
  __syncthreads();

  const int wv = tid >> 6;
  const int lane = tid & 63;
  const int l15 = lane & 15;
  const int lg = lane >> 4;
  const int rA0 = wv * 32 + l15;

  f32x4 acc[2][8] = {};
#pragma unroll
  for (int t = 0; t < 4; ++t) {
    const int kb = t * 64 + lg * 16;  // bytes: k = t*32 + lg*8
    short8 a0 = *reinterpret_cast<const short8*>((char*)Xs + swz(rA0, kb));
    short8 a1 = *reinterpret_cast<const short8*>((char*)Xs + swz(rA0 + 16, kb));
#pragma unroll
    for (int n = 0; n < 8; ++n) {
      short8 b = *reinterpret_cast<const short8*>((char*)Wsh + swz(n * 16 + l15, kb));
      acc[0][n] = __builtin_amdgcn_mfma_f32_16x16x32_bf16(a0, b, acc[0][n], 0, 0, 0);
      acc[1][n] = __builtin_amdgcn_mfma_f32_16x16x32_bf16(a1, b, acc[1][n], 0, 0, 0);
    }
  }

#pragma unroll
  for (int m = 0; m < 2; ++m) {
#pragma unroll
    for (int n = 0; n < 8; ++n) {
      const int col = n * 16 + l15;
      float bv = 0.f;
      if (BIAS) bv = bias[col];
#pragma unroll
      for (int r = 0; r < 4; ++r) {
        int lrow = wv * 32 + m * 16 + lg * 4 + r;
        if (lrow < limit) {
          float v = acc[m][n][r] + bv;
          if (OBF16)
            reinterpret_cast<unsigned short*>(out)[(row0 + lrow) * D + col] = f2bf(v);
          else
            reinterpret_cast<float*>(out)[(row0 + lrow) * D + col] = v;
        }
      }
    }
  }
}

// ---------------- gather (CSR, no atomics, MLP-optimized) ----------------
// 16 lanes per dst node; each lane owns 16B (8 bf16) of the 256B row.
// Slot indices prefetched 16-wide (one coalesced load per chunk), broadcast
// via __shfl(width=16); row loads hand-unrolled 4-wide for 4 loads in flight.

__device__ inline void addbf8(float* sum, uint4 v) {
  sum[0] += __uint_as_float(v.x << 16);
  sum[1] += __uint_as_float(v.x & 0xffff0000u);
  sum[2] += __uint_as_float(v.y << 16);
  sum[3] += __uint_as_float(v.y & 0xffff0000u);
  sum[4] += __uint_as_float(v.z << 16);
  sum[5] += __uint_as_float(v.z & 0xffff0000u);
  sum[6] += __uint_as_float(v.w << 16);
  sum[7] += __uint_as_float(v.w & 0xffff0000u);
}

__device__ inline float gather_one(const uint4* __restrict__ Y4,
                                   const int* __restrict__ rowptr,
                                   const int* __restrict__ slots,
                                   int node, int lane, float* sum) {
  int s0 = rowptr[node], s1 = rowptr[node + 1];
  for (int chunk = s0; chunk < s1; chunk += 16) {
    int idx = chunk + lane;
    int pre = (idx < s1) ? slots[idx] : 0;
    int m = s1 - chunk; if (m > 16) m = 16;
    int j = 0;
    for (; j + 4 <= m; j += 4) {
      int sA = __shfl(pre, j, 16);
      int sB = __shfl(pre, j + 1, 16);
      int sC = __shfl(pre, j + 2, 16);
      int sD = __shfl(pre, j + 3, 16);
      uint4 vA = Y4[(size_t)sA * 16 + lane];
      uint4 vB = Y4[(size_t)sB * 16 + lane];
      uint4 vC = Y4[(size_t)sC * 16 + lane];
      uint4 vD = Y4[(size_t)sD * 16 + lane];
      addbf8(sum, vA); addbf8(sum, vB); addbf8(sum, vC); addbf8(sum, vD);
    }
    for (; j < m; ++j) {
      int s = __shfl(pre, j, 16);
      addbf8(sum, Y4[(size_t)s * 16 + lane]);
    }
  }
  return 1.0f / fmaxf((float)(s1 - s0), 1.0f);
}

template<int NREL>
__global__ __launch_bounds__(256) void gatherN_kernel(
    const unsigned short* __restrict__ Y0, const int* __restrict__ rp0, const int* __restrict__ sl0,
    const unsigned short* __restrict__ Y1, const int* __restrict__ rp1, const int* __restrict__ sl1,
    float* __restrict__ acc, int nnodes) {
  long g = (long)blockIdx.x * 256 + threadIdx.x;
  int node = (int)(g >> 4);
  if (node >= nnodes) return;
  int lane = (int)(g & 15);

  float t0[8] = {}, t1[8] = {};
  float inv0 = gather_one(reinterpret_cast<const uint4*>(Y0), rp0, sl0, node, lane, t0);
  float inv1 = 0.f;
  if (NREL == 2)
    inv1 = gather_one(reinterpret_cast<const uint4*>(Y1), rp1, sl1, node, lane, t1);

  float* ap = acc + (size_t)node * D + lane * 8;
  float4 a0 = *reinterpret_cast<float4*>(ap);
  float4 a1 = *reinterpret_cast<float4*>(ap + 4);
  a0.x += t0[0] * inv0; a0.y += t0[1] * inv0;
  a0.z += t0[2] * inv0; a0.w += t0[3] * inv0;
  a1.x += t0[4] * inv0; a1.y += t0[5] * inv0;
  a1.z += t0[6] * inv0; a1.w += t0[7] * inv0;
  if (NREL == 2) {
    a0.x += t1[0] * inv1; a0.y += t1[1] * inv1;
    a0.z += t1[2] * inv1; a0.w += t1[3] * inv1;
    a1.x += t1[4] * inv1; a1.y += t1[5] * inv1;
    a1.z += t1[6] * inv1; a1.w += t1[7] * inv1;
  }
  *reinterpret_cast<float4*>(ap) = a0;
  *reinterpret_cast<float4*>(ap + 4) = a1;
}

// ---------------- launch ----------------

extern "C" void kernel_launch(void* const* d_in, const int* in_sizes, int n_in,
                              void* d_out, int out_size, void* d_ws, size_t ws_size,
                              hipStream_t stream) {
  const float* x_drug = (const float*)d_in[0];
  const float* x_prot = (const float*)d_in[1];
  const float* Wl0dp = (const float*)d_in[2];  const float* b0dp = (const float*)d_in[3];  const float* Wr0dp = (const float*)d_in[4];
  const float* Wl0pd = (const float*)d_in[5];  const float* b0pd = (const float*)d_in[6];  const float* Wr0pd = (const float*)d_in[7];
  const float* Wl0dd = (const float*)d_in[8];  const float* b0dd = (const float*)d_in[9];  const float* Wr0dd = (const float*)d_in[10];
  const float* Wl1dp = (const float*)d_in[11]; const float* b1dp = (const float*)d_in[12]; const float* Wr1dp = (const float*)d_in[13];
  const float* Wl1pd = (const float*)d_in[14]; const float* b1pd = (const float*)d_in[15]; const float* Wr1pd = (const float*)d_in[16];
  const float* Wl1dd = (const float*)d_in[17]; const float* b1dd = (const float*)d_in[18]; const float* Wr1dd = (const float*)d_in[19];
  const int* e_dp_s = (const int*)d_in[20]; const int* e_dp_d = (const int*)d_in[21];
  const int* e_pd_s = (const int*)d_in[22]; const int* e_pd_d = (const int*)d_in[23];
  const int* e_dd_s = (const int*)d_in[24]; const int* e_dd_d = (const int*)d_in[25];

  const int ND = in_sizes[0] / D;   // 200000
  const int NP = in_sizes[1] / D;   // 100000
  const int E_dp = in_sizes[20], E_pd = in_sizes[22], E_dd = in_sizes[24];

  // workspace layout (bytes budget ~242 MB, under round-1-proven 259 MB)
  float* ws = (float*)d_ws;
  float* accD = ws;                               // ND*D f32
  float* accP = accD + (size_t)ND * D;            // NP*D f32
  unsigned short* ybuf1 = (unsigned short*)(accP + (size_t)NP * D);  // ND*D bf16
  unsigned short* ybuf2 = ybuf1 + (size_t)ND * D;                    // NP*D bf16
  float* Wsum = (float*)(ybuf2 + (size_t)NP * D); // D*D
  float* bsum = Wsum + D * D;                     // D
  int* iws    = (int*)(bsum + D);
  int* rp_dp  = iws;                              // NP+1
  int* rp_pd  = rp_dp + (NP + 2);                 // ND+1
  int* rp_dd  = rp_pd + (ND + 2);                 // ND+1
  int* sl_dp  = rp_dd + (ND + 2);                 // E_dp
  int* sl_pd  = sl_dp + E_dp;                     // E_pd
  int* sl_dd  = sl_pd + E_pd;                     // E_dd
  int* cnt    = sl_dd + E_dd;                     // max(ND,NP)
  int* bsums  = cnt + ND;                         // <=1024

  auto cdiv = [](long a, long b) { return (int)((a + b - 1) / b); };

  auto build_csr = [&](const int* esrc, const int* edst, int ne, int ndst,
                       int* rowptr, int* slots) {
    int nb = cdiv(ndst, 256);
    hipMemsetAsync(cnt, 0, (size_t)ndst * sizeof(int), stream);
    count_int_kernel<<<cdiv(ne, 256), 256, 0, stream>>>(edst, cnt, ne);
    blocksum_kernel<<<nb, 256, 0, stream>>>(cnt, bsums, ndst);
    scan_bsums_kernel<<<1, 256, 0, stream>>>(bsums, nb);
    scan_finalize_kernel<<<nb, 256, 0, stream>>>(cnt, bsums, rowptr, ndst, ne);
    hipMemcpyAsync(cnt, rowptr, (size_t)ndst * sizeof(int), hipMemcpyDeviceToDevice, stream);
    fill_kernel<<<cdiv(ne, 256), 256, 0, stream>>>(esrc, edst, cnt, slots, ne);
  };

  auto gemm = [&](const float* X, const float* W, const float* bias,
                  void* out, int n, bool relu, bool bias_on, bool obf16) {
    dim3 grid(cdiv(n, 128));
    if (relu) {
      if (obf16)        gemm128_kernel<true, false, true><<<grid, 256, 0, stream>>>(X, W, bias, out, n);
      else if (bias_on) gemm128_kernel<true, true, false><<<grid, 256, 0, stream>>>(X, W, bias, out, n);
      else              gemm128_kernel<true, false, false><<<grid, 256, 0, stream>>>(X, W, bias, out, n);
    } else {
      if (obf16)        gemm128_kernel<false, false, true><<<grid, 256, 0, stream>>>(X, W, bias, out, n);
      else if (bias_on) gemm128_kernel<false, true, false><<<grid, 256, 0, stream>>>(X, W, bias, out, n);
      else              gemm128_kernel<false, false, false><<<grid, 256, 0, stream>>>(X, W, bias, out, n);
    }
  };

  // ---- CSRs (layer-invariant, built once) ----
  build_csr(e_dp_s, e_dp_d, E_dp, NP, rp_dp, sl_dp);
  build_csr(e_pd_s, e_pd_d, E_pd, ND, rp_pd, sl_pd);
  build_csr(e_dd_s, e_dd_d, E_dd, ND, rp_dd, sl_dd);

  auto run_layer = [&](const float* xd, const float* xp,
                       const float* Wldp, const float* bdp, const float* Wrdp,
                       const float* Wlpd, const float* bpd, const float* Wrpd,
                       const float* Wldd, const float* bdd, const float* Wrdd,
                       float* outD, float* outP, bool relu_in) {
    addvec_kernel<<<cdiv(D * D, 256), 256, 0, stream>>>(Wrpd, Wrdd, Wsum, D * D);
    addvec_kernel<<<1, 256, 0, stream>>>(bpd, bdd, bsum, D);
    // init accumulators with lin_r(x_dst) + bias (f32 out)
    gemm(xp, Wrdp, bdp, outP, NP, relu_in, true, false);
    gemm(xd, Wsum, bsum, outD, ND, relu_in, true, false);
    // dd: drugs -> drugs (ybuf1, ND rows); pd: proteins -> drugs (ybuf2, NP rows)
    gemm(xd, Wldd, nullptr, ybuf1, ND, relu_in, false, true);
    gemm(xp, Wlpd, nullptr, ybuf2, NP, relu_in, false, true);
    // fused dual gather into drug accumulator (single RMW)
    gatherN_kernel<2><<<cdiv((long)ND * 16, 256), 256, 0, stream>>>(
        ybuf2, rp_pd, sl_pd, ybuf1, rp_dd, sl_dd, outD, ND);
    // dp: drugs -> proteins (reuse ybuf1)
    gemm(xd, Wldp, nullptr, ybuf1, ND, relu_in, false, true);
    gatherN_kernel<1><<<cdiv((long)NP * 16, 256), 256, 0, stream>>>(
        ybuf1, rp_dp, sl_dp, nullptr, nullptr, nullptr, outP, NP);
  };

  float* outD1 = (float*)d_out;
  float* outP1 = outD1 + (size_t)ND * D;

  run_layer(x_drug, x_prot,
            Wl0dp, b0dp, Wr0dp, Wl0pd, b0pd, Wr0pd, Wl0dd, b0dd, Wr0dd,
            accD, accP, /*relu_in=*/false);
  run_layer(accD, accP,
            Wl1dp, b1dp, Wr1dp, Wl1pd, b1pd, Wr1pd, Wl1dd, b1dd, Wr1dd,
            outD1, outP1, /*relu_in=*/true);
}

// Round 5
// 819.695 us; speedup vs baseline: 12.1954x; 1.3904x over previous
//
#include <hip/hip_runtime.h>

#define D 128

using short8 = __attribute__((ext_vector_type(8))) short;
using f32x4 = __attribute__((ext_vector_type(4))) float;

__device__ inline unsigned short f2bf(float f) {
  unsigned u = __float_as_uint(f);
  u += 0x7fffu + ((u >> 16) & 1u);  // RNE
  return (unsigned short)(u >> 16);
}

// swizzled byte offset within a [128 rows][128 bf16] LDS tile (G4 fix)
__device__ inline int swz(int r, int kbyte) {
  return ((r << 8) + kbyte) ^ ((r & 7) << 4);
}

// relu on two packed bf16
__device__ inline unsigned relu_pk(unsigned w) {
  if (w & 0x8000u) w &= 0xffff0000u;
  if (w & 0x80000000u) w &= 0x0000ffffu;
  return w;
}

// ---------------- CSR build ----------------

__global__ __launch_bounds__(256) void count_int_kernel(const int* __restrict__ dst,
                                                        int* __restrict__ cnt, int n) {
  int i = blockIdx.x * 256 + threadIdx.x;
  if (i < n) atomicAdd(&cnt[dst[i]], 1);
}

__global__ __launch_bounds__(256) void blocksum_kernel(const int* __restrict__ cnt,
                                                       int* __restrict__ bsums, int n) {
  __shared__ int sh[256];
  int i = blockIdx.x * 256 + threadIdx.x;
  sh[threadIdx.x] = (i < n) ? cnt[i] : 0;
  __syncthreads();
#pragma unroll
  for (int off = 128; off > 0; off >>= 1) {
    if (threadIdx.x < off) sh[threadIdx.x] += sh[threadIdx.x + off];
    __syncthreads();
  }
  if (threadIdx.x == 0) bsums[blockIdx.x] = sh[0];
}

__global__ __launch_bounds__(256) void scan_bsums_kernel(int* __restrict__ bsums, int nb) {
  __shared__ int sh[256];
  __shared__ int carry;
  if (threadIdx.x == 0) carry = 0;
  __syncthreads();
  for (int base = 0; base < nb; base += 256) {
    int i = base + threadIdx.x;
    int v = (i < nb) ? bsums[i] : 0;
    sh[threadIdx.x] = v;
    __syncthreads();
#pragma unroll
    for (int off = 1; off < 256; off <<= 1) {
      int t = (threadIdx.x >= off) ? sh[threadIdx.x - off] : 0;
      __syncthreads();
      sh[threadIdx.x] += t;
      __syncthreads();
    }
    int incl = sh[threadIdx.x];
    if (i < nb) bsums[i] = carry + incl - v;  // exclusive
    __syncthreads();
    if (threadIdx.x == 0) carry += sh[255];
    __syncthreads();
  }
}

__global__ __launch_bounds__(256) void scan_finalize_kernel(const int* __restrict__ cnt,
                                                            const int* __restrict__ bsums,
                                                            int* __restrict__ rowptr,
                                                            int n, int total) {
  __shared__ int sh[256];
  int i = blockIdx.x * 256 + threadIdx.x;
  int v = (i < n) ? cnt[i] : 0;
  sh[threadIdx.x] = v;
  __syncthreads();
#pragma unroll
  for (int off = 1; off < 256; off <<= 1) {
    int t = (threadIdx.x >= off) ? sh[threadIdx.x - off] : 0;
    __syncthreads();
    sh[threadIdx.x] += t;
    __syncthreads();
  }
  if (i < n) {
    rowptr[i] = bsums[blockIdx.x] + sh[threadIdx.x] - v;
    if (i == n - 1) rowptr[n] = total;
  }
}

__global__ __launch_bounds__(256) void fill_kernel(const int* __restrict__ src,
                                                   const int* __restrict__ dst,
                                                   int* __restrict__ cursor,
                                                   int* __restrict__ slots, int n) {
  int i = blockIdx.x * 256 + threadIdx.x;
  if (i < n) {
    int pos = atomicAdd(&cursor[dst[i]], 1);
    slots[pos] = src[i];
  }
}

// ---------------- weight prep: 5 bf16 matrices + bsum ----------------
// Wb layout: [0]=Wrpd+Wrdd (drug lin_r), [1]=Wldd, [2]=Wldp, [3]=Wrdp, [4]=Wlpd

__global__ __launch_bounds__(256) void prep_weights_kernel(
    const float* __restrict__ Wrpd, const float* __restrict__ Wrdd,
    const float* __restrict__ Wldd, const float* __restrict__ Wldp,
    const float* __restrict__ Wrdp, const float* __restrict__ Wlpd,
    const float* __restrict__ bpd, const float* __restrict__ bdd,
    unsigned short* __restrict__ Wb, float* __restrict__ bsum) {
  int i = blockIdx.x * 256 + threadIdx.x;
  const int M = D * D;
  if (i < M)           Wb[i] = f2bf(Wrpd[i] + Wrdd[i - 0 * M]);
  else if (i < 2 * M)  Wb[i] = f2bf(Wldd[i - 1 * M]);
  else if (i < 3 * M)  Wb[i] = f2bf(Wldp[i - 2 * M]);
  else if (i < 4 * M)  Wb[i] = f2bf(Wrdp[i - 3 * M]);
  else if (i < 5 * M)  Wb[i] = f2bf(Wlpd[i - 4 * M]);
  if (i < D) bsum[i] = bpd[i] + bdd[i];
}

// ---------------- fragment loaders ----------------

template<typename XT, bool RELU>
__device__ inline short8 ld_frag(const XT* __restrict__ p, bool valid) {
  if constexpr (sizeof(XT) == 4) {  // f32
    float4 v0 = make_float4(0.f, 0.f, 0.f, 0.f), v1 = v0;
    if (valid) {
      v0 = *reinterpret_cast<const float4*>(p);
      v1 = *reinterpret_cast<const float4*>(p + 4);
    }
    if (RELU) {
      v0.x = fmaxf(v0.x, 0.f); v0.y = fmaxf(v0.y, 0.f);
      v0.z = fmaxf(v0.z, 0.f); v0.w = fmaxf(v0.w, 0.f);
      v1.x = fmaxf(v1.x, 0.f); v1.y = fmaxf(v1.y, 0.f);
      v1.z = fmaxf(v1.z, 0.f); v1.w = fmaxf(v1.w, 0.f);
    }
    short8 s;
    s[0] = (short)f2bf(v0.x); s[1] = (short)f2bf(v0.y);
    s[2] = (short)f2bf(v0.z); s[3] = (short)f2bf(v0.w);
    s[4] = (short)f2bf(v1.x); s[5] = (short)f2bf(v1.y);
    s[6] = (short)f2bf(v1.z); s[7] = (short)f2bf(v1.w);
    return s;
  } else {  // bf16
    uint4 u = make_uint4(0, 0, 0, 0);
    if (valid) u = *reinterpret_cast<const uint4*>(p);
    if (RELU) { u.x = relu_pk(u.x); u.y = relu_pk(u.y); u.z = relu_pk(u.z); u.w = relu_pk(u.w); }
    union { uint4 u; short8 s; } cv; cv.u = u;
    return cv.s;
  }
}

// ---------------- fused multi-head GEMM ----------------
// out_h[n,128] = (relu? X)[n,128] @ W_h[128,128]^T for NH heads; head0 gets +bias
// and writes f32 or bf16 (OUT0_BF16); heads 1.. write bf16.
// W (NH matrices) staged once per block in LDS (swizzled). X fragments loaded
// directly global->regs (no barrier in tile loop). Grid-stride over 128-row tiles.

template<typename XT, bool RELU, int NH, bool OUT0_BF16>
__global__ __launch_bounds__(256) void fused_gemm_kernel(
    const XT* __restrict__ X, const unsigned short* __restrict__ Wb,
    const float* __restrict__ bias0, void* __restrict__ out0,
    unsigned short* __restrict__ out1, unsigned short* __restrict__ out2,
    int nrows, int ntiles) {
  __shared__ short Wsh[NH * D * D];
  const int tid = threadIdx.x;

  for (int i = tid; i < NH * 4096; i += 256) {  // ushort4 granules
    int mat = i >> 12;
    int idx = i & 4095;
    int r = idx >> 5;
    int kb = (idx & 31) * 8;
    ushort4 w = reinterpret_cast<const ushort4*>(Wb)[i];
    *reinterpret_cast<ushort4*>((char*)(Wsh + mat * D * D) + swz(r, kb)) = w;
  }
  __syncthreads();

  const int wv = tid >> 6, lane = tid & 63;
  const int l15 = lane & 15, lg = lane >> 4;

  float bias_c[8];
#pragma unroll
  for (int n = 0; n < 8; ++n) bias_c[n] = bias0[n * 16 + l15];

  for (int tile = blockIdx.x; tile < ntiles; tile += gridDim.x) {
    const size_t row0 = (size_t)tile * 128;
    const int limit = (int)min((long)128, (long)nrows - (long)row0);
    const int rA = wv * 32 + l15;  // local row of frag a0; a1 = +16

    short8 a[2][4];
    const bool full = (limit == 128);
#pragma unroll
    for (int t = 0; t < 4; ++t) {
      int k0 = t * 32 + lg * 8;
      a[0][t] = ld_frag<XT, RELU>(X + (row0 + rA) * D + k0, full || (rA < limit));
      a[1][t] = ld_frag<XT, RELU>(X + (row0 + rA + 16) * D + k0, full || (rA + 16 < limit));
    }

    f32x4 acc[NH][2][8] = {};
#pragma unroll
    for (int t = 0; t < 4; ++t) {
      const int kb = t * 64 + lg * 16;
#pragma unroll
      for (int h = 0; h < NH; ++h) {
        const char* base = (const char*)(Wsh + h * D * D);
#pragma unroll
        for (int n = 0; n < 8; ++n) {
          short8 b = *reinterpret_cast<const short8*>(base + swz(n * 16 + l15, kb));
          acc[h][0][n] = __builtin_amdgcn_mfma_f32_16x16x32_bf16(a[0][t], b, acc[h][0][n], 0, 0, 0);
          acc[h][1][n] = __builtin_amdgcn_mfma_f32_16x16x32_bf16(a[1][t], b, acc[h][1][n], 0, 0, 0);
        }
      }
    }

    // epilogue: C/D layout col=lane&15 (via B), row=lg*4+reg (via A) [m89]
#pragma unroll
    for (int m = 0; m < 2; ++m) {
#pragma unroll
      for (int n = 0; n < 8; ++n) {
        const int col = n * 16 + l15;
#pragma unroll
        for (int r = 0; r < 4; ++r) {
          int lrow = wv * 32 + m * 16 + lg * 4 + r;
          if (lrow < limit) {
            size_t o = (row0 + lrow) * D + col;
            float v0 = acc[0][m][n][r] + bias_c[n];
            if (OUT0_BF16) reinterpret_cast<unsigned short*>(out0)[o] = f2bf(v0);
            else           reinterpret_cast<float*>(out0)[o] = v0;
            if (NH >= 2) out1[o] = f2bf(acc[1][m][n][r]);
            if (NH >= 3) out2[o] = f2bf(acc[2][m][n][r]);
          }
        }
      }
    }
  }
}

// ---------------- gather (CSR, no atomics, MLP-optimized) ----------------
// 16 lanes per dst node; lane owns 16B (8 bf16) of the 256B row.

__device__ inline void addbf8(float* sum, uint4 v) {
  sum[0] += __uint_as_float(v.x << 16);
  sum[1] += __uint_as_float(v.x & 0xffff0000u);
  sum[2] += __uint_as_float(v.y << 16);
  sum[3] += __uint_as_float(v.y & 0xffff0000u);
  sum[4] += __uint_as_float(v.z << 16);
  sum[5] += __uint_as_float(v.z & 0xffff0000u);
  sum[6] += __uint_as_float(v.w << 16);
  sum[7] += __uint_as_float(v.w & 0xffff0000u);
}

__device__ inline float gather_one(const uint4* __restrict__ Y4,
                                   const int* __restrict__ rowptr,
                                   const int* __restrict__ slots,
                                   int node, int lane, float* sum) {
  int s0 = rowptr[node], s1 = rowptr[node + 1];
  for (int chunk = s0; chunk < s1; chunk += 16) {
    int idx = chunk + lane;
    int pre = (idx < s1) ? slots[idx] : 0;
    int m = s1 - chunk; if (m > 16) m = 16;
    int j = 0;
    for (; j + 4 <= m; j += 4) {
      int sA = __shfl(pre, j, 16);
      int sB = __shfl(pre, j + 1, 16);
      int sC = __shfl(pre, j + 2, 16);
      int sD = __shfl(pre, j + 3, 16);
      uint4 vA = Y4[(size_t)sA * 16 + lane];
      uint4 vB = Y4[(size_t)sB * 16 + lane];
      uint4 vC = Y4[(size_t)sC * 16 + lane];
      uint4 vD = Y4[(size_t)sD * 16 + lane];
      addbf8(sum, vA); addbf8(sum, vB); addbf8(sum, vC); addbf8(sum, vD);
    }
    for (; j < m; ++j) {
      int s = __shfl(pre, j, 16);
      addbf8(sum, Y4[(size_t)s * 16 + lane]);
    }
  }
  return 1.0f / fmaxf((float)(s1 - s0), 1.0f);
}

template<int NREL, bool ACC_BF16>
__global__ __launch_bounds__(256) void gatherN_kernel(
    const unsigned short* __restrict__ Y0, const int* __restrict__ rp0, const int* __restrict__ sl0,
    const unsigned short* __restrict__ Y1, const int* __restrict__ rp1, const int* __restrict__ sl1,
    void* __restrict__ acc, int nnodes) {
  long g = (long)blockIdx.x * 256 + threadIdx.x;
  int node = (int)(g >> 4);
  if (node >= nnodes) return;
  int lane = (int)(g & 15);

  float t0[8] = {}, t1[8] = {};
  float inv0 = gather_one(reinterpret_cast<const uint4*>(Y0), rp0, sl0, node, lane, t0);
  float inv1 = 0.f;
  if (NREL == 2)
    inv1 = gather_one(reinterpret_cast<const uint4*>(Y1), rp1, sl1, node, lane, t1);

  float a[8];
  if (ACC_BF16) {
    unsigned short* ap = (unsigned short*)acc + (size_t)node * D + lane * 8;
    uint4 u = *reinterpret_cast<uint4*>(ap);
    a[0] = __uint_as_float(u.x << 16); a[1] = __uint_as_float(u.x & 0xffff0000u);
    a[2] = __uint_as_float(u.y << 16); a[3] = __uint_as_float(u.y & 0xffff0000u);
    a[4] = __uint_as_float(u.z << 16); a[5] = __uint_as_float(u.z & 0xffff0000u);
    a[6] = __uint_as_float(u.w << 16); a[7] = __uint_as_float(u.w & 0xffff0000u);
#pragma unroll
    for (int i = 0; i < 8; ++i) {
      a[i] += t0[i] * inv0;
      if (NREL == 2) a[i] += t1[i] * inv1;
    }
    uint4 o;
    o.x = (unsigned)f2bf(a[0]) | ((unsigned)f2bf(a[1]) << 16);
    o.y = (unsigned)f2bf(a[2]) | ((unsigned)f2bf(a[3]) << 16);
    o.z = (unsigned)f2bf(a[4]) | ((unsigned)f2bf(a[5]) << 16);
    o.w = (unsigned)f2bf(a[6]) | ((unsigned)f2bf(a[7]) << 16);
    *reinterpret_cast<uint4*>(ap) = o;
  } else {
    float* ap = (float*)acc + (size_t)node * D + lane * 8;
    float4 a0 = *reinterpret_cast<float4*>(ap);
    float4 a1 = *reinterpret_cast<float4*>(ap + 4);
    a[0] = a0.x; a[1] = a0.y; a[2] = a0.z; a[3] = a0.w;
    a[4] = a1.x; a[5] = a1.y; a[6] = a1.z; a[7] = a1.w;
#pragma unroll
    for (int i = 0; i < 8; ++i) {
      a[i] += t0[i] * inv0;
      if (NREL == 2) a[i] += t1[i] * inv1;
    }
    *reinterpret_cast<float4*>(ap) = make_float4(a[0], a[1], a[2], a[3]);
    *reinterpret_cast<float4*>(ap + 4) = make_float4(a[4], a[5], a[6], a[7]);
  }
}

// ---------------- launch ----------------

extern "C" void kernel_launch(void* const* d_in, const int* in_sizes, int n_in,
                              void* d_out, int out_size, void* d_ws, size_t ws_size,
                              hipStream_t stream) {
  const float* x_drug = (const float*)d_in[0];
  const float* x_prot = (const float*)d_in[1];
  const float* Wl0dp = (const float*)d_in[2];  const float* b0dp = (const float*)d_in[3];  const float* Wr0dp = (const float*)d_in[4];
  const float* Wl0pd = (const float*)d_in[5];  const float* b0pd = (const float*)d_in[6];  const float* Wr0pd = (const float*)d_in[7];
  const float* Wl0dd = (const float*)d_in[8];  const float* b0dd = (const float*)d_in[9];  const float* Wr0dd = (const float*)d_in[10];
  const float* Wl1dp = (const float*)d_in[11]; const float* b1dp = (const float*)d_in[12]; const float* Wr1dp = (const float*)d_in[13];
  const float* Wl1pd = (const float*)d_in[14]; const float* b1pd = (const float*)d_in[15]; const float* Wr1pd = (const float*)d_in[16];
  const float* Wl1dd = (const float*)d_in[17]; const float* b1dd = (const float*)d_in[18]; const float* Wr1dd = (const float*)d_in[19];
  const int* e_dp_s = (const int*)d_in[20]; const int* e_dp_d = (const int*)d_in[21];
  const int* e_pd_s = (const int*)d_in[22]; const int* e_pd_d = (const int*)d_in[23];
  const int* e_dd_s = (const int*)d_in[24]; const int* e_dd_d = (const int*)d_in[25];

  const int ND = in_sizes[0] / D;   // 200000
  const int NP = in_sizes[1] / D;   // 100000
  const int E_dp = in_sizes[20], E_pd = in_sizes[22], E_dd = in_sizes[24];

  // workspace layout (~218 MB, under proven 242)
  unsigned short* accD  = (unsigned short*)d_ws;              // ND*D bf16 (layer-0 drug out)
  unsigned short* accP  = accD + (size_t)ND * D;              // NP*D bf16
  unsigned short* bufdd = accP + (size_t)NP * D;              // ND*D bf16
  unsigned short* bufdp = bufdd + (size_t)ND * D;             // ND*D bf16
  unsigned short* bufpd = bufdp + (size_t)ND * D;             // NP*D bf16
  unsigned short* Wb    = bufpd + (size_t)NP * D;             // 5*D*D bf16
  float* bsum  = (float*)(Wb + 5 * D * D);                    // D f32
  int* rp_dp  = (int*)(bsum + D);                             // NP+1
  int* rp_pd  = rp_dp + (NP + 2);                             // ND+1
  int* rp_dd  = rp_pd + (ND + 2);                             // ND+1
  int* sl_dp  = rp_dd + (ND + 2);                             // E_dp
  int* sl_pd  = sl_dp + E_dp;                                 // E_pd
  int* sl_dd  = sl_pd + E_pd;                                 // E_dd
  int* cnt    = sl_dd + E_dd;                                 // max(ND,NP)
  int* bsums  = cnt + ND;                                     // <=1024

  auto cdiv = [](long a, long b) { return (int)((a + b - 1) / b); };

  auto build_csr = [&](const int* esrc, const int* edst, int ne, int ndst,
                       int* rowptr, int* slots) {
    int nb = cdiv(ndst, 256);
    hipMemsetAsync(cnt, 0, (size_t)ndst * sizeof(int), stream);
    count_int_kernel<<<cdiv(ne, 256), 256, 0, stream>>>(edst, cnt, ne);
    blocksum_kernel<<<nb, 256, 0, stream>>>(cnt, bsums, ndst);
    scan_bsums_kernel<<<1, 256, 0, stream>>>(bsums, nb);
    scan_finalize_kernel<<<nb, 256, 0, stream>>>(cnt, bsums, rowptr, ndst, ne);
    hipMemcpyAsync(cnt, rowptr, (size_t)ndst * sizeof(int), hipMemcpyDeviceToDevice, stream);
    fill_kernel<<<cdiv(ne, 256), 256, 0, stream>>>(esrc, edst, cnt, slots, ne);
  };

  build_csr(e_dp_s, e_dp_d, E_dp, NP, rp_dp, sl_dp);
  build_csr(e_pd_s, e_pd_d, E_pd, ND, rp_pd, sl_pd);
  build_csr(e_dd_s, e_dd_d, E_dd, ND, rp_dd, sl_dd);

  const int tilesD = cdiv(ND, 128), tilesP = cdiv(NP, 128);

  // ---------- layer 0 (X = f32, no relu-in, outputs bf16 to ws) ----------
  prep_weights_kernel<<<cdiv(5 * D * D, 256), 256, 0, stream>>>(
      Wr0pd, Wr0dd, Wl0dd, Wl0dp, Wr0dp, Wl0pd, b0pd, b0dd, Wb, bsum);
  fused_gemm_kernel<float, false, 3, true><<<256, 256, 0, stream>>>(
      x_drug, Wb, bsum, accD, bufdd, bufdp, ND, tilesD);
  fused_gemm_kernel<float, false, 2, true><<<512, 256, 0, stream>>>(
      x_prot, Wb + 3 * D * D, b0dp, accP, bufpd, nullptr, NP, tilesP);
  gatherN_kernel<2, true><<<cdiv((long)ND * 16, 256), 256, 0, stream>>>(
      bufpd, rp_pd, sl_pd, bufdd, rp_dd, sl_dd, accD, ND);
  gatherN_kernel<1, true><<<cdiv((long)NP * 16, 256), 256, 0, stream>>>(
      bufdp, rp_dp, sl_dp, nullptr, nullptr, nullptr, accP, NP);

  // ---------- layer 1 (X = bf16 + relu-in, outputs f32 to d_out) ----------
  float* outD1 = (float*)d_out;
  float* outP1 = outD1 + (size_t)ND * D;
  prep_weights_kernel<<<cdiv(5 * D * D, 256), 256, 0, stream>>>(
      Wr1pd, Wr1dd, Wl1dd, Wl1dp, Wr1dp, Wl1pd, b1pd, b1dd, Wb, bsum);
  fused_gemm_kernel<unsigned short, true, 3, false><<<256, 256, 0, stream>>>(
      accD, Wb, bsum, outD1, bufdd, bufdp, ND, tilesD);
  fused_gemm_kernel<unsigned short, true, 2, false><<<512, 256, 0, stream>>>(
      accP, Wb + 3 * D * D, b1dp, outP1, bufpd, nullptr, NP, tilesP);
  gatherN_kernel<2, false><<<cdiv((long)ND * 16, 256), 256, 0, stream>>>(
      bufpd, rp_pd, sl_pd, bufdd, rp_dd, sl_dd, outD1, ND);
  gatherN_kernel<1, false><<<cdiv((long)NP * 16, 256), 256, 0, stream>>>(
      bufdp, rp_dp, sl_dp, nullptr, nullptr, nullptr, outP1, NP);
}